// Round 1
// baseline (769.818 us; speedup 1.0000x reference)
//
#include <hip/hip_runtime.h>
#include <math.h>

#define S_LEN 2048
#define HID 4096
#define NH 32
#define NKV 8
#define HD 128
#define NQKV 6144

typedef __bf16 bf16x8 __attribute__((ext_vector_type(8)));
typedef float f32x4 __attribute__((ext_vector_type(4)));

__device__ inline short f2bf(float f) {
  union { float f; unsigned u; } a; a.f = f;
  unsigned r = a.u + 0x7fffu + ((a.u >> 16) & 1u);
  return (short)(r >> 16);
}

// ---------------- elementwise casts ----------------
__global__ __launch_bounds__(256) void cast_h(const float* __restrict__ X,
                                              short* __restrict__ Y, int n4) {
  int i = blockIdx.x * 256 + threadIdx.x;
  if (i >= n4) return;
  float4 v = ((const float4*)X)[i];
  short4 o;
  o.x = f2bf(v.x); o.y = f2bf(v.y); o.z = f2bf(v.z); o.w = f2bf(v.w);
  ((short4*)Y)[i] = o;
}

// W (4096 x Ncols) fp32 row-major  ->  Wt (Ncols x 4096) bf16
__global__ __launch_bounds__(256) void cast_wt(const float* __restrict__ W,
                                               short* __restrict__ Wt, int Ncols) {
  __shared__ float t[32][33];
  int n0 = blockIdx.x * 32, k0 = blockIdx.y * 32;
  int tx = threadIdx.x, ty = threadIdx.y;
  for (int j = 0; j < 4; j++)
    t[ty + 8 * j][tx] = W[(size_t)(k0 + ty + 8 * j) * Ncols + n0 + tx];
  __syncthreads();
  for (int j = 0; j < 4; j++)
    Wt[(size_t)(n0 + ty + 8 * j) * 4096 + k0 + tx] = f2bf(t[tx][ty + 8 * j]);
}

// ---------------- RoPE ----------------
__global__ void rope_table(const int* __restrict__ pos_ids, float* __restrict__ tc,
                           float* __restrict__ ts) {
  int p = blockIdx.x, i = threadIdx.x;
  float pos = (float)pos_ids[p];
  float inv = powf(10000.0f, -((float)(2 * i)) * (1.0f / 128.0f));
  float a = pos * inv;
  tc[p * 64 + i] = cosf(a);
  ts[p * 64 + i] = sinf(a);
}

// in-place on C (2048 x 6144): heads 0..31 = Q at col h*128; 32..39 = K at 4096+(h-32)*128
__global__ void rope_apply(float* __restrict__ C, const float* __restrict__ tc,
                           const float* __restrict__ ts) {
  int p = blockIdx.x, hh = blockIdx.y, i = threadIdx.x;
  int col = (hh < 32) ? (hh * 128 + i) : (4096 + (hh - 32) * 128 + i);
  float c = tc[p * 64 + i], s = ts[p * 64 + i];
  float* row = C + (size_t)p * NQKV;
  float x1 = row[col], x2 = row[col + 64];
  row[col] = x1 * c - x2 * s;
  row[col + 64] = x2 * c + x1 * s;
}

// ---------------- absmax + quantize ----------------
__global__ __launch_bounds__(256) void absmax_k(const float* __restrict__ base, int bits,
                                                unsigned* __restrict__ slot) {
  const int n = 2048 << bits;
  const int mask = (1 << bits) - 1;
  float m = 0.f;
  for (int idx = blockIdx.x * blockDim.x + threadIdx.x; idx < n;
       idx += gridDim.x * blockDim.x)
    m = fmaxf(m, fabsf(base[(size_t)(idx >> bits) * NQKV + (idx & mask)]));
  for (int off = 32; off; off >>= 1) m = fmaxf(m, __shfl_xor(m, off, 64));
  __shared__ float red[4];
  if ((threadIdx.x & 63) == 0) red[threadIdx.x >> 6] = m;
  __syncthreads();
  if (threadIdx.x == 0) {
    m = fmaxf(fmaxf(red[0], red[1]), fmaxf(red[2], red[3]));
    atomicMax(slot, __float_as_uint(m));
  }
}

__global__ __launch_bounds__(256) void quant_q(const float* __restrict__ C,
                                               const unsigned* __restrict__ scal,
                                               short* __restrict__ Qi) {
  int idx = blockIdx.x * 256 + threadIdx.x;  // 2048*4096 threads
  float scale = __uint_as_float(scal[0]) * (1.0f / 127.0f);
  int p = idx >> 12, c = idx & 4095;
  Qi[idx] = f2bf(rintf(C[(size_t)p * NQKV + c] / scale));
}

__global__ __launch_bounds__(256) void quant_k(const float* __restrict__ C,
                                               const unsigned* __restrict__ scal,
                                               short* __restrict__ Ki) {
  int idx = blockIdx.x * 256 + threadIdx.x;  // 8*2048*128 threads
  float scale = __uint_as_float(scal[1]) * (1.0f / 127.0f);
  int h = idx >> 18, p = (idx >> 7) & 2047, d = idx & 127;
  Ki[idx] = f2bf(rintf(C[(size_t)p * NQKV + 4096 + h * 128 + d] / scale));
}

// V -> Vt (NKV, HD, S) transposed, quantized to integer-valued bf16
__global__ __launch_bounds__(256) void quant_vt(const float* __restrict__ C,
                                                const unsigned* __restrict__ scal,
                                                short* __restrict__ Vt) {
  __shared__ float t[64][65];
  int h = blockIdx.x, pt = blockIdx.y, dt = blockIdx.z;
  float scale = __uint_as_float(scal[2]) * (1.0f / 127.0f);
  int tid = threadIdx.x;
  for (int j = 0; j < 16; j++) {
    int q = tid + 256 * j;
    int pl = q >> 6, dl = q & 63;
    t[dl][pl] = C[(size_t)(pt * 64 + pl) * NQKV + 5120 + h * 128 + dt * 64 + dl];
  }
  __syncthreads();
  for (int j = 0; j < 16; j++) {
    int q = tid + 256 * j;
    int dl = q >> 6, pl = q & 63;
    Vt[(size_t)(h * 128 + dt * 64 + dl) * 2048 + pt * 64 + pl] =
        f2bf(rintf(t[dl][pl] / scale));
  }
}

// ---------------- bf16 GEMM, C = A(MxK) * B^T(NxK), fp32 out ----------------
__global__ __launch_bounds__(256) void gemm_bt(const short* __restrict__ A, int lda,
                                               const short* __restrict__ B,
                                               float* __restrict__ C, int ldc, int K) {
  __shared__ alignas(16) short As[128 * 40];  // rows padded 32->40 shorts
  __shared__ alignas(16) short Bs[128 * 40];
  const int tid = threadIdx.x;
  const int wave = tid >> 6, lane = tid & 63;
  const int quad = lane >> 4, l15 = lane & 15;
  const int m0 = blockIdx.y * 128, n0 = blockIdx.x * 128;
  const int wm = (wave >> 1) * 64, wn = (wave & 1) * 64;
  f32x4 acc[4][4] = {};
  const int sr = tid >> 2, ss = tid & 3;  // stage rows 0..63 (+64), 16B segs 0..3
  const short* Ag = A + (size_t)(m0 + sr) * lda + ss * 8;
  const short* Bg = B + (size_t)(n0 + sr) * K + ss * 8;
  int4* As4 = (int4*)As;
  int4* Bs4 = (int4*)Bs;
  const int li = sr * 5 + ss;
  for (int k0 = 0; k0 < K; k0 += 32) {
    int4 a0 = *(const int4*)(Ag + k0);
    int4 a1 = *(const int4*)(Ag + (size_t)64 * lda + k0);
    int4 b0 = *(const int4*)(Bg + k0);
    int4 b1 = *(const int4*)(Bg + (size_t)64 * K + k0);
    __syncthreads();
    As4[li] = a0; As4[li + 320] = a1;
    Bs4[li] = b0; Bs4[li + 320] = b1;
    __syncthreads();
    bf16x8 af[4], bfr[4];
    for (int t = 0; t < 4; t++) {
      af[t]  = *(const bf16x8*)&As[(wm + t * 16 + l15) * 40 + quad * 8];
      bfr[t] = *(const bf16x8*)&Bs[(wn + t * 16 + l15) * 40 + quad * 8];
    }
    for (int tm = 0; tm < 4; tm++)
      for (int tn = 0; tn < 4; tn++)
        acc[tm][tn] =
            __builtin_amdgcn_mfma_f32_16x16x32_bf16(af[tm], bfr[tn], acc[tm][tn], 0, 0, 0);
  }
  for (int tm = 0; tm < 4; tm++)
    for (int tn = 0; tn < 4; tn++) {
      const int row = m0 + wm + tm * 16 + quad * 4;
      const int col = n0 + wn + tn * 16 + l15;
      for (int r = 0; r < 4; r++) C[(size_t)(row + r) * ldc + col] = acc[tm][tn][r];
    }
}

// ---------------- fused causal GQA attention (flash-style) ----------------
__global__ __launch_bounds__(256) void attn_fused(const short* __restrict__ Qi,
                                                  const short* __restrict__ Ki,
                                                  const short* __restrict__ Vt,
                                                  const unsigned* __restrict__ scal,
                                                  short* __restrict__ Oa) {
  __shared__ alignas(16) short Ks[64 * 136];   // [key][d], row stride 136 shorts
  __shared__ alignas(16) short Vs[128 * 72];   // [d][key], row stride 72
  __shared__ alignas(16) short Ps[4][32 * 72]; // per-wave P, [row][key], stride 72
  const int tid = threadIdx.x;
  const int wave = tid >> 6, lane = tid & 63;
  const int quad = lane >> 4, l15 = lane & 15;
  const int h = blockIdx.x & 31, qt = blockIdx.x >> 5;
  const int kvh = h >> 2;
  const float qs = __uint_as_float(scal[0]) * (1.0f / 127.0f);
  const float ksc = __uint_as_float(scal[1]) * (1.0f / 127.0f);
  const float vsc = __uint_as_float(scal[2]) * (1.0f / 127.0f);
  const float sscale = qs * ksc * 0.08838834764831845f;  // 1/sqrt(128)
  const int qrow = qt * 128 + wave * 32;

  bf16x8 aq[2][4];
  for (int tm = 0; tm < 2; tm++)
    for (int kc = 0; kc < 4; kc++)
      aq[tm][kc] = *(const bf16x8*)(Qi + (size_t)(qrow + tm * 16 + l15) * 4096 + h * 128 +
                                    kc * 32 + quad * 8);

  f32x4 o[2][8] = {};
  float mrow[2][4], lrow[2][4];
  for (int tm = 0; tm < 2; tm++)
    for (int r = 0; r < 4; r++) { mrow[tm][r] = -INFINITY; lrow[tm][r] = 0.f; }

  const int nkt = qt * 2 + 2;
  const short* Kg = Ki + (size_t)kvh * S_LEN * HD;
  const short* Vg = Vt + (size_t)kvh * HD * S_LEN;
  int4* Ks4 = (int4*)Ks;
  int4* Vs4 = (int4*)Vs;

  for (int kt = 0; kt < nkt; kt++) {
    const int k0 = kt * 64;
    __syncthreads();  // previous iteration's LDS reads complete
    for (int j = 0; j < 4; j++) {  // K tile: 1024 x 16B
      int c = tid + 256 * j;
      int kr = c >> 4, seg = c & 15;
      Ks4[kr * 17 + seg] = *(const int4*)(Kg + (size_t)(k0 + kr) * HD + seg * 8);
    }
    for (int j = 0; j < 4; j++) {  // V tile: 1024 x 16B
      int c = tid + 256 * j;
      int d = c >> 3, seg = c & 7;
      Vs4[d * 9 + seg] = *(const int4*)(Vg + (size_t)d * S_LEN + k0 + seg * 8);
    }
    __syncthreads();

    f32x4 sf[2][4];
    for (int tn = 0; tn < 4; tn++) {
      f32x4 s0 = {0.f, 0.f, 0.f, 0.f}, s1 = {0.f, 0.f, 0.f, 0.f};
      for (int kc = 0; kc < 4; kc++) {
        bf16x8 bk = *(const bf16x8*)&Ks[(tn * 16 + l15) * 136 + kc * 32 + quad * 8];
        s0 = __builtin_amdgcn_mfma_f32_16x16x32_bf16(aq[0][kc], bk, s0, 0, 0, 0);
        s1 = __builtin_amdgcn_mfma_f32_16x16x32_bf16(aq[1][kc], bk, s1, 0, 0, 0);
      }
      sf[0][tn] = s0; sf[1][tn] = s1;
    }

    for (int tm = 0; tm < 2; tm++) {
      for (int r = 0; r < 4; r++) {
        const int grow = qrow + tm * 16 + quad * 4 + r;
        float mx = -3.0e38f;
        for (int tn = 0; tn < 4; tn++) {
          float v = sf[tm][tn][r] * sscale;
          if (k0 + tn * 16 + l15 > grow) v = -3.0e38f;  // causal mask
          sf[tm][tn][r] = v;
          mx = fmaxf(mx, v);
        }
        for (int off = 1; off < 16; off <<= 1) mx = fmaxf(mx, __shfl_xor(mx, off, 16));
        const float mo = mrow[tm][r];
        const float mn = fmaxf(mo, mx);
        const float alpha = __expf(mo - mn);
        float rs = 0.f;
        for (int tn = 0; tn < 4; tn++) {
          float p = __expf(sf[tm][tn][r] - mn);
          rs += p;
          Ps[wave][(tm * 16 + quad * 4 + r) * 72 + tn * 16 + l15] = f2bf(p);
        }
        for (int off = 1; off < 16; off <<= 1) rs += __shfl_xor(rs, off, 16);
        lrow[tm][r] = lrow[tm][r] * alpha + rs;
        mrow[tm][r] = mn;
        for (int tn = 0; tn < 8; tn++) o[tm][tn][r] *= alpha;
      }
    }
    __syncthreads();  // P visible before A-operand reads

    for (int kk = 0; kk < 2; kk++) {
      bf16x8 ap0 = *(const bf16x8*)&Ps[wave][(l15) * 72 + kk * 32 + quad * 8];
      bf16x8 ap1 = *(const bf16x8*)&Ps[wave][(16 + l15) * 72 + kk * 32 + quad * 8];
      for (int tn = 0; tn < 8; tn++) {
        bf16x8 bv = *(const bf16x8*)&Vs[(tn * 16 + l15) * 72 + kk * 32 + quad * 8];
        o[0][tn] = __builtin_amdgcn_mfma_f32_16x16x32_bf16(ap0, bv, o[0][tn], 0, 0, 0);
        o[1][tn] = __builtin_amdgcn_mfma_f32_16x16x32_bf16(ap1, bv, o[1][tn], 0, 0, 0);
      }
    }
  }

  for (int tm = 0; tm < 2; tm++)
    for (int r = 0; r < 4; r++) {
      const int grow = qrow + tm * 16 + quad * 4 + r;
      const float sc = vsc / lrow[tm][r];
      for (int tn = 0; tn < 8; tn++)
        Oa[(size_t)grow * 4096 + h * 128 + tn * 16 + l15] = f2bf(o[tm][tn][r] * sc);
    }
}

// ---------------- launch ----------------
extern "C" void kernel_launch(void* const* d_in, const int* in_sizes, int n_in,
                              void* d_out, int out_size, void* d_ws, size_t ws_size,
                              hipStream_t stream) {
  (void)in_sizes; (void)n_in; (void)out_size; (void)ws_size;
  const float* H  = (const float*)d_in[0];
  const int*   pos = (const int*)d_in[2];
  const float* wq = (const float*)d_in[3];
  const float* wk = (const float*)d_in[4];
  const float* wv = (const float*)d_in[5];
  const float* wo = (const float*)d_in[6];
  char* ws = (char*)d_ws;
  short* Hb   = (short*)(ws + 0);           // 16 MB
  short* Wt   = (short*)(ws + 16777216);    // 48 MB (6144 x 4096 bf16, qkv^T concat)
  short* Wot  = (short*)(ws + 67108864);    // 32 MB
  float* C    = (float*)(ws + 100663296);   // 48 MB (2048 x 6144 f32)
  short* Qi   = (short*)(ws + 150994944);   // 16 MB
  short* Ki   = (short*)(ws + 167772160);   // 4 MB (8,2048,128)
  short* Vt   = (short*)(ws + 171966464);   // 4 MB (8,128,2048)
  short* Oa   = (short*)(ws + 176160768);   // 16 MB
  float* tc   = (float*)(ws + 192937984);   // 512 KB
  float* tsn  = (float*)(ws + 193462272);   // 512 KB
  unsigned* scal = (unsigned*)(ws + 193986560);

  hipLaunchKernelGGL(cast_h, dim3(8192), dim3(256), 0, stream, H, Hb, 2097152);
  hipLaunchKernelGGL(cast_wt, dim3(128, 128), dim3(32, 8), 0, stream, wq, Wt, 4096);
  hipLaunchKernelGGL(cast_wt, dim3(32, 128), dim3(32, 8), 0, stream, wk,
                     Wt + (size_t)4096 * 4096, 1024);
  hipLaunchKernelGGL(cast_wt, dim3(32, 128), dim3(32, 8), 0, stream, wv,
                     Wt + (size_t)5120 * 4096, 1024);
  hipLaunchKernelGGL(cast_wt, dim3(128, 128), dim3(32, 8), 0, stream, wo, Wot, 4096);
  hipLaunchKernelGGL(rope_table, dim3(2048), dim3(64), 0, stream, pos, tc, tsn);
  hipLaunchKernelGGL(gemm_bt, dim3(48, 16), dim3(256), 0, stream, Hb, 4096, Wt, C, 6144,
                     4096);
  hipLaunchKernelGGL(rope_apply, dim3(2048, 40), dim3(64), 0, stream, C, tc, tsn);
  hipMemsetAsync(scal, 0, 16, stream);
  hipLaunchKernelGGL(absmax_k, dim3(1024), dim3(256), 0, stream, C, 12, scal + 0);
  hipLaunchKernelGGL(absmax_k, dim3(512), dim3(256), 0, stream, C + 4096, 10, scal + 1);
  hipLaunchKernelGGL(absmax_k, dim3(512), dim3(256), 0, stream, C + 5120, 10, scal + 2);
  hipLaunchKernelGGL(quant_q, dim3(32768), dim3(256), 0, stream, C, scal, Qi);
  hipLaunchKernelGGL(quant_k, dim3(8192), dim3(256), 0, stream, C, scal, Ki);
  hipLaunchKernelGGL(quant_vt, dim3(8, 32, 2), dim3(256), 0, stream, C, scal, Vt);
  hipLaunchKernelGGL(attn_fused, dim3(512), dim3(256), 0, stream, Qi, Ki, Vt, scal, Oa);
  hipLaunchKernelGGL(gemm_bt, dim3(32, 16), dim3(256), 0, stream, Oa, 4096, Wot,
                     (float*)d_out, 4096, 4096);
}